// Round 1
// baseline (109.314 us; speedup 1.0000x reference)
//
#include <hip/hip_runtime.h>
#include <hip/hip_bf16.h>
#include <math.h>

// Problem constants
#define TGT 560
#define B_ 2
#define K_ 1600
#define D_ 1024
#define C_ 256
#define N_ 32
#define P_ 40
#define KC_ 32      // k-chunks in k3
#define KCHUNK 50   // K_/KC_

// ws layout (float offsets)
#define OFF_W   ((size_t)0)                    // 560*40 = 22400
#define OFF_IFN (OFF_W + (size_t)TGT * P_)     // 3200
#define OFF_IEN (OFF_IFN + (size_t)B_ * K_)    // 256
#define OFF_V   (OFF_IEN + (size_t)C_)         // B*N*K = 102400
#define OFF_GP  (OFF_V + (size_t)B_ * N_ * K_) // B*KC*N*D = 2097152

// ---------------- Kernel 1: inverse row norms (feats + emb) and bicubic weight matrix W ----------
__global__ __launch_bounds__(256) void k1_norms_w(const float* __restrict__ feats,
                                                  const float* __restrict__ emb,
                                                  float* __restrict__ ws) {
    __shared__ float red[4];
    const int r = blockIdx.x;
    const int t = threadIdx.x;
    if (r < B_ * K_ + C_) {
        const float* src;
        float* dst;
        if (r < B_ * K_) { src = feats + (size_t)r * D_; dst = ws + OFF_IFN + r; }
        else             { src = emb + (size_t)(r - B_ * K_) * D_; dst = ws + OFF_IEN + (r - B_ * K_); }
        float4 v = ((const float4*)src)[t];
        float s = v.x * v.x + v.y * v.y + v.z * v.z + v.w * v.w;
        #pragma unroll
        for (int off = 32; off > 0; off >>= 1) s += __shfl_down(s, off, 64);
        if ((t & 63) == 0) red[t >> 6] = s;
        __syncthreads();
        if (t == 0) {
            float tot = red[0] + red[1] + red[2] + red[3];
            *dst = 1.0f / sqrtf(tot);   // eps fold: rel err ~1e-11, negligible
        }
    } else {
        // bicubic weight matrix: W[h][p], exactly mirrors jax.image compute_weight_mat
        int idx = (r - (B_ * K_ + C_)) * 256 + t;
        if (idx < TGT * P_) {
            int h = idx / P_;
            int p = idx - h * P_;
            float sf = ((float)h + 0.5f) * (1.0f / 14.0f) - 0.5f;
            int jf = (int)floorf(sf);
            float norm = 0.f, wp = 0.f;
            #pragma unroll
            for (int dj = -1; dj <= 2; ++dj) {
                int j = jf + dj;
                if (j < 0 || j >= P_) continue;
                float x = fabsf(sf - (float)j);
                float w = ((1.5f * x - 2.5f) * x) * x + 1.f;      // Keys a=-0.5, jax order
                if (x >= 1.f) w = ((-0.5f * x + 2.5f) * x - 4.f) * x + 2.f;
                if (x >= 2.f) w = 0.f;
                norm += w;
                if (j == p) wp = w;
            }
            ws[OFF_W + idx] = wp / norm;  // per-output normalization (edge renorm) like jax
        }
    }
}

// ---------------- Kernel 2: per-box separable weights wy/wx and v[b][n][k] ----------------------
__global__ __launch_bounds__(256) void k2_boxw(const int* __restrict__ boxes,
                                               float* __restrict__ ws) {
    __shared__ float part[256];
    __shared__ float wxy[80];    // [0..39]=wy, [40..79]=wx
    const int bn = blockIdx.x;
    const int b = bn >> 5, n = bn & 31;
    const int t = threadIdx.x;
    const int* bx = boxes + bn * 4;
    const int xmin = bx[0], ymin = bx[1], xmax = bx[2], ymax = bx[3];
    const float invcnt = 1.0f / ((float)(ymax - 1 - ymin) * (float)(xmax - 1 - xmin));

    const int axis = t >> 7;        // 0: y (rows, p), 1: x (cols, q)
    const int rr = t & 127;
    const int p = rr % 40;
    const int slice = rr / 40;      // 0..2 active
    float partial = 0.f;
    if (rr < 120) {
        int lo = (axis ? xmin : ymin) + slice;
        int hi = (axis ? xmax : ymax) - 2;   // mask: r in [min, max-2] inclusive
        const float* Wp = ws + OFF_W;
        for (int h = lo; h <= hi; h += 3) partial += Wp[h * P_ + p];
    }
    part[t] = partial;
    __syncthreads();
    if (t < 80) {
        int a = t / 40, pp = t % 40;
        int base = a * 128;
        wxy[t] = part[base + pp] + part[base + 40 + pp] + part[base + 80 + pp];
    }
    __syncthreads();
    const float* ifn = ws + OFF_IFN + (size_t)b * K_;
    float* v = ws + OFF_V + ((size_t)b * N_ + n) * K_;
    for (int k = t; k < K_; k += 256) {
        int pq = k / P_;
        int q = k - pq * P_;
        v[k] = wxy[pq] * wxy[40 + q] * ifn[k] * invcnt;
    }
}

// ---------------- Kernel 3: g partials: gp[b][kc][n][d] = sum_{k in chunk} v[b][n][k]*feats[b][k][d]
__global__ __launch_bounds__(256) void k3_gp(const float* __restrict__ feats,
                                             const float* __restrict__ wsv,
                                             float* __restrict__ gp) {
    __shared__ float vlds[KCHUNK * N_];
    const int bid = blockIdx.x;          // 256 blocks: b(2) x kc(32) x dt(4)
    const int b = bid >> 7;
    const int rest = bid & 127;
    const int kc = rest >> 2;
    const int dt = rest & 3;
    const int t = threadIdx.x;
    const int k0 = kc * KCHUNK;

    for (int i = t; i < KCHUNK * N_; i += 256) {
        int n = i / KCHUNK;
        int kk = i - n * KCHUNK;
        vlds[kk * N_ + n] = wsv[((size_t)b * N_ + n) * K_ + k0 + kk];
    }
    __syncthreads();

    float acc[N_];
    #pragma unroll
    for (int n = 0; n < N_; ++n) acc[n] = 0.f;

    const float* fp = feats + ((size_t)b * K_ + k0) * D_ + dt * 256 + t;
    #pragma unroll 2
    for (int kk = 0; kk < KCHUNK; ++kk) {
        float f = fp[(size_t)kk * D_];
        #pragma unroll
        for (int n = 0; n < N_; ++n) acc[n] = fmaf(vlds[kk * N_ + n], f, acc[n]);
    }
    float* o = gp + (((size_t)b * KC_ + kc) * N_) * D_ + dt * 256 + t;
    #pragma unroll
    for (int n = 0; n < N_; ++n) o[(size_t)n * D_] = acc[n];
}

// ---------------- Kernel 4: reduce gp over kc, then out[bn][c] = (1/|e_c|) * <g, emb[c]> ---------
__global__ __launch_bounds__(256) void k4_out(const float* __restrict__ emb,
                                              const float* __restrict__ gp,
                                              const float* __restrict__ ien,
                                              float* __restrict__ out) {
    __shared__ float4 g4[D_ / 4];
    __shared__ float part[256];
    const int bid = blockIdx.x;      // 256 blocks: bn(64) x ct(4)
    const int bn = bid >> 2;
    const int ct = bid & 3;
    const int b = bn >> 5, n = bn & 31;
    const int t = threadIdx.x;

    float4 a = {0.f, 0.f, 0.f, 0.f};
    #pragma unroll 4
    for (int kc = 0; kc < KC_; ++kc) {
        const float4* src = (const float4*)gp + (((size_t)b * KC_ + kc) * N_ + n) * (D_ / 4) + t;
        float4 x = *src;
        a.x += x.x; a.y += x.y; a.z += x.z; a.w += x.w;
    }
    g4[t] = a;
    __syncthreads();

    const int cl = t & 63;
    const int dq = t >> 6;              // wave-uniform -> broadcast LDS reads
    const int c = ct * 64 + cl;
    const float4* e4 = (const float4*)(emb + (size_t)c * D_) + dq * 64;
    const float4* gg = g4 + dq * 64;
    float partial = 0.f;
    #pragma unroll 8
    for (int i = 0; i < 64; ++i) {
        float4 e = e4[i];
        float4 g = gg[i];
        partial += e.x * g.x + e.y * g.y + e.z * g.z + e.w * g.w;
    }
    part[t] = partial;
    __syncthreads();
    if (t < 64) {
        int c2 = ct * 64 + t;
        float val = part[t] + part[64 + t] + part[128 + t] + part[192 + t];
        out[(size_t)bn * C_ + c2] = val * ien[c2];
    }
}

extern "C" void kernel_launch(void* const* d_in, const int* in_sizes, int n_in,
                              void* d_out, int out_size, void* d_ws, size_t ws_size,
                              hipStream_t stream) {
    const float* feats = (const float*)d_in[0];
    const float* emb   = (const float*)d_in[1];
    const int*   boxes = (const int*)d_in[2];
    float* out = (float*)d_out;
    float* ws  = (float*)d_ws;

    const int norm_blocks = B_ * K_ + C_;                 // 3456
    const int w_blocks = (TGT * P_ + 255) / 256;          // 88
    k1_norms_w<<<norm_blocks + w_blocks, 256, 0, stream>>>(feats, emb, ws);
    k2_boxw<<<B_ * N_, 256, 0, stream>>>(boxes, ws);
    k3_gp<<<B_ * KC_ * 4, 256, 0, stream>>>(feats, ws + OFF_V, ws + OFF_GP);
    k4_out<<<B_ * N_ * 4, 256, 0, stream>>>(emb, ws + OFF_GP, ws + OFF_IEN, out);
}

// Round 2
// 96.521 us; speedup vs baseline: 1.1325x; 1.1325x over previous
//
#include <hip/hip_runtime.h>
#include <hip/hip_bf16.h>
#include <math.h>

// Problem constants
#define TGT 560
#define B_ 2
#define K_ 1600
#define D_ 1024
#define C_ 256
#define N_ 32
#define P_ 40
#define KC_ 32      // k-chunks in kB
#define KCHUNK 50   // K_/KC_

// ws layout (float offsets)
#define OFF_IFN ((size_t)0)                      // B*K = 3200 inverse feat norms
#define OFF_IEN (OFF_IFN + (size_t)B_ * K_)      // C = 256 inverse emb norms
#define OFF_BOXW (OFF_IEN + (size_t)C_)          // B*N*80 (wy*invcnt | wx)
#define OFF_GP  ((size_t)16384)                  // B*KC*N*D = 2,097,152

// ---- Kernel A: inverse row norms (feats+emb) AND per-box separable bicubic weights ----
__global__ __launch_bounds__(256) void kA(const float* __restrict__ feats,
                                          const float* __restrict__ emb,
                                          const int* __restrict__ boxes,
                                          float* __restrict__ ws) {
    __shared__ float shm[80];
    const int r = blockIdx.x;
    const int t = threadIdx.x;
    if (r < B_ * K_ + C_) {
        // ---- row norm block ----
        const float* src;
        float* dst;
        if (r < B_ * K_) { src = feats + (size_t)r * D_; dst = ws + OFF_IFN + r; }
        else             { src = emb + (size_t)(r - B_ * K_) * D_; dst = ws + OFF_IEN + (r - B_ * K_); }
        float4 v = ((const float4*)src)[t];
        float s = v.x * v.x + v.y * v.y + v.z * v.z + v.w * v.w;
        #pragma unroll
        for (int off = 32; off > 0; off >>= 1) s += __shfl_down(s, off, 64);
        if ((t & 63) == 0) shm[t >> 6] = s;
        __syncthreads();
        if (t == 0) {
            float tot = shm[0] + shm[1] + shm[2] + shm[3];
            *dst = 1.0f / sqrtf(tot);   // eps fold: rel err ~1e-11, negligible
        }
    } else {
        // ---- box-weight block: wy[p] = sum_{h in [ymin,ymax-2]} Wrow(h)[p], same for x ----
        const int bn = r - (B_ * K_ + C_);
        if (t < 80) shm[t] = 0.f;
        __syncthreads();
        const int* bx = boxes + bn * 4;
        const int xmin = bx[0], ymin = bx[1], xmax = bx[2], ymax = bx[3];
        const float invcnt = 1.0f / ((float)(ymax - 1 - ymin) * (float)(xmax - 1 - xmin));
        const int axis = t >> 7;                       // 0 -> y, 1 -> x
        const int rr = t & 127;
        const int lo = (axis ? xmin : ymin);
        const int hi = (axis ? xmax : ymax) - 2;       // inclusive
        for (int h = lo + rr; h <= hi; h += 128) {
            float sf = ((float)h + 0.5f) * (1.0f / 14.0f) - 0.5f;
            int jf = (int)floorf(sf);
            float w[4];
            float norm = 0.f;
            #pragma unroll
            for (int dj = -1; dj <= 2; ++dj) {
                int j = jf + dj;
                float x = fabsf(sf - (float)j);
                float wv = ((1.5f * x - 2.5f) * x) * x + 1.f;            // |x|<1 (Keys a=-0.5)
                if (x >= 1.f) wv = ((-0.5f * x + 2.5f) * x - 4.f) * x + 2.f; // 1<=|x|<2
                if (x >= 2.f) wv = 0.f;
                if (j < 0 || j >= P_) wv = 0.f;        // edge: tap outside -> renorm below
                w[dj + 1] = wv;
                norm += wv;
            }
            float inv = 1.0f / norm;
            #pragma unroll
            for (int dj = 0; dj < 4; ++dj) {
                int j = jf - 1 + dj;
                if (w[dj] != 0.f) atomicAdd(&shm[axis * P_ + j], w[dj] * inv);
            }
        }
        __syncthreads();
        if (t < 80) {
            float val = shm[t];
            if (t < P_) val *= invcnt;                 // fold 1/count into wy
            ws[OFF_BOXW + (size_t)bn * 80 + t] = val;
        }
    }
}

// ---- Kernel B: gp[b][kc][n][d] = sum_{k in chunk} v[b,n,k] * feats[b,k,d],
//      v built in-block from box weights * inv feat norm ----
__global__ __launch_bounds__(256) void kB(const float* __restrict__ feats,
                                          const float* __restrict__ ws,
                                          float* __restrict__ gp) {
    __shared__ float sw[N_ * 80];
    __shared__ float vlds[KCHUNK * N_];
    const int bid = blockIdx.x;          // 256 blocks: b(2) x kc(32) x dt(4)
    const int b = bid >> 7;
    const int rest = bid & 127;
    const int kc = rest >> 2;
    const int dt = rest & 3;
    const int t = threadIdx.x;
    const int k0 = kc * KCHUNK;

    for (int i = t; i < N_ * 80; i += 256)
        sw[i] = ws[OFF_BOXW + (size_t)b * N_ * 80 + i];
    __syncthreads();
    const float* ifn = ws + OFF_IFN + (size_t)b * K_;
    for (int i = t; i < KCHUNK * N_; i += 256) {
        int kk = i >> 5, n = i & 31;
        int k = k0 + kk;
        int pq = k / P_;
        int q = k - pq * P_;
        vlds[kk * N_ + n] = sw[n * 80 + pq] * sw[n * 80 + P_ + q] * ifn[k];
    }
    __syncthreads();

    float acc[N_];
    #pragma unroll
    for (int n = 0; n < N_; ++n) acc[n] = 0.f;

    const float* fp = feats + ((size_t)b * K_ + k0) * D_ + dt * 256 + t;
    #pragma unroll
    for (int g = 0; g < 5; ++g) {
        float f[10];
        #pragma unroll
        for (int u = 0; u < 10; ++u) f[u] = fp[(size_t)(g * 10 + u) * D_];  // 10 loads in flight
        #pragma unroll
        for (int u = 0; u < 10; ++u) {
            const float4* vp = (const float4*)&vlds[(g * 10 + u) * N_];
            #pragma unroll
            for (int j = 0; j < 8; ++j) {            // broadcast b128 reads: 8 instead of 32
                float4 v4 = vp[j];
                acc[4 * j + 0] = fmaf(v4.x, f[u], acc[4 * j + 0]);
                acc[4 * j + 1] = fmaf(v4.y, f[u], acc[4 * j + 1]);
                acc[4 * j + 2] = fmaf(v4.z, f[u], acc[4 * j + 2]);
                acc[4 * j + 3] = fmaf(v4.w, f[u], acc[4 * j + 3]);
            }
        }
    }
    float* o = gp + (((size_t)b * KC_ + kc) * N_) * D_ + dt * 256 + t;
    #pragma unroll
    for (int n = 0; n < N_; ++n) o[(size_t)n * D_] = acc[n];
}

// ---- Kernel C: reduce gp over kc, then out[bn][c] = (1/|e_c|) * <g, emb[c]> ----
__global__ __launch_bounds__(256) void kC(const float* __restrict__ emb,
                                          const float* __restrict__ gp,
                                          const float* __restrict__ ien,
                                          float* __restrict__ out) {
    __shared__ float4 g4[D_ / 4];
    __shared__ float part[256];
    const int bid = blockIdx.x;      // 256 blocks: bn(64) x ct(4)
    const int bn = bid >> 2;
    const int ct = bid & 3;
    const int b = bn >> 5, n = bn & 31;
    const int t = threadIdx.x;

    float4 a = {0.f, 0.f, 0.f, 0.f};
    #pragma unroll 4
    for (int kc = 0; kc < KC_; ++kc) {
        const float4* src = (const float4*)gp + (((size_t)b * KC_ + kc) * N_ + n) * (D_ / 4) + t;
        float4 x = *src;
        a.x += x.x; a.y += x.y; a.z += x.z; a.w += x.w;
    }
    g4[t] = a;
    __syncthreads();

    const int cl = t & 63;
    const int dq = t >> 6;              // wave-uniform -> broadcast LDS reads
    const int c = ct * 64 + cl;
    const float4* e4 = (const float4*)(emb + (size_t)c * D_) + dq * 64;
    const float4* gg = g4 + dq * 64;
    float partial = 0.f;
    #pragma unroll 8
    for (int i = 0; i < 64; ++i) {
        float4 e = e4[i];
        float4 g = gg[i];
        partial += e.x * g.x + e.y * g.y + e.z * g.z + e.w * g.w;
    }
    part[t] = partial;
    __syncthreads();
    if (t < 64) {
        int c2 = ct * 64 + t;
        float val = part[t] + part[64 + t] + part[128 + t] + part[192 + t];
        out[(size_t)bn * C_ + c2] = val * ien[c2];
    }
}

extern "C" void kernel_launch(void* const* d_in, const int* in_sizes, int n_in,
                              void* d_out, int out_size, void* d_ws, size_t ws_size,
                              hipStream_t stream) {
    const float* feats = (const float*)d_in[0];
    const float* emb   = (const float*)d_in[1];
    const int*   boxes = (const int*)d_in[2];
    float* out = (float*)d_out;
    float* ws  = (float*)d_ws;

    kA<<<B_ * K_ + C_ + B_ * N_, 256, 0, stream>>>(feats, emb, boxes, ws);
    kB<<<B_ * KC_ * 4, 256, 0, stream>>>(feats, ws, ws + OFF_GP);
    kC<<<B_ * N_ * 4, 256, 0, stream>>>(emb, ws + OFF_GP, ws + OFF_IEN, out);
}

// Round 3
// 94.864 us; speedup vs baseline: 1.1523x; 1.0175x over previous
//
#include <hip/hip_runtime.h>
#include <hip/hip_bf16.h>
#include <math.h>

// Problem constants
#define TGT 560
#define B_ 2
#define K_ 1600
#define D_ 1024
#define C_ 256
#define N_ 32
#define P_ 40
#define KC_ 32      // k-chunks in kB
#define KCHUNK 50   // K_/KC_

// ws layout (float offsets)
#define OFF_IFN ((size_t)0)                      // B*K = 3200 inverse feat norms
#define OFF_IEN (OFF_IFN + (size_t)B_ * K_)      // C = 256 inverse emb norms
#define OFF_BOXW (OFF_IEN + (size_t)C_)          // B*N*80 (wy*invcnt | wx)
#define OFF_G   ((size_t)16384)                  // B*N*D = 65536 floats (256 KB)

// ---- Kernel A: inverse row norms (feats+emb), per-box separable bicubic weights, zero g ----
__global__ __launch_bounds__(256) void kA(const float* __restrict__ feats,
                                          const float* __restrict__ emb,
                                          const int* __restrict__ boxes,
                                          float* __restrict__ ws) {
    __shared__ float shm[80];
    const int r = blockIdx.x;
    const int t = threadIdx.x;
    if (r < B_ * K_ + C_) {
        // ---- row norm block ----
        const float* src;
        float* dst;
        if (r < B_ * K_) { src = feats + (size_t)r * D_; dst = ws + OFF_IFN + r; }
        else             { src = emb + (size_t)(r - B_ * K_) * D_; dst = ws + OFF_IEN + (r - B_ * K_); }
        float4 v = ((const float4*)src)[t];
        float s = v.x * v.x + v.y * v.y + v.z * v.z + v.w * v.w;
        #pragma unroll
        for (int off = 32; off > 0; off >>= 1) s += __shfl_down(s, off, 64);
        if ((t & 63) == 0) shm[t >> 6] = s;
        __syncthreads();
        if (t == 0) {
            float tot = shm[0] + shm[1] + shm[2] + shm[3];
            *dst = 1.0f / sqrtf(tot);   // eps fold: rel err ~1e-11, negligible
        }
    } else {
        // ---- box-weight block (one per bn): also zero-init g[bn][:] for kB's atomics ----
        const int bn = r - (B_ * K_ + C_);
        ((float4*)(ws + OFF_G + (size_t)bn * D_))[t] = make_float4(0.f, 0.f, 0.f, 0.f);
        if (t < 80) shm[t] = 0.f;
        __syncthreads();
        const int* bx = boxes + bn * 4;
        const int xmin = bx[0], ymin = bx[1], xmax = bx[2], ymax = bx[3];
        const float invcnt = 1.0f / ((float)(ymax - 1 - ymin) * (float)(xmax - 1 - xmin));
        const int axis = t >> 7;                       // 0 -> y, 1 -> x
        const int rr = t & 127;
        const int lo = (axis ? xmin : ymin);
        const int hi = (axis ? xmax : ymax) - 2;       // inclusive
        for (int h = lo + rr; h <= hi; h += 128) {
            float sf = ((float)h + 0.5f) * (1.0f / 14.0f) - 0.5f;
            int jf = (int)floorf(sf);
            float w[4];
            float norm = 0.f;
            #pragma unroll
            for (int dj = -1; dj <= 2; ++dj) {
                int j = jf + dj;
                float x = fabsf(sf - (float)j);
                float wv = ((1.5f * x - 2.5f) * x) * x + 1.f;            // |x|<1 (Keys a=-0.5)
                if (x >= 1.f) wv = ((-0.5f * x + 2.5f) * x - 4.f) * x + 2.f; // 1<=|x|<2
                if (x >= 2.f) wv = 0.f;
                if (j < 0 || j >= P_) wv = 0.f;        // edge: tap outside -> renorm below
                w[dj + 1] = wv;
                norm += wv;
            }
            float inv = 1.0f / norm;
            #pragma unroll
            for (int dj = 0; dj < 4; ++dj) {
                int j = jf - 1 + dj;
                if (w[dj] != 0.f) atomicAdd(&shm[axis * P_ + j], w[dj] * inv);
            }
        }
        __syncthreads();
        if (t < 80) {
            float val = shm[t];
            if (t < P_) val *= invcnt;                 // fold 1/count into wy
            ws[OFF_BOXW + (size_t)bn * 80 + t] = val;
        }
    }
}

// ---- Kernel B: g[b][n][d] += sum_{k in chunk} v[b,n,k] * feats[b,k,d] (device atomics) ----
__global__ __launch_bounds__(256) void kB(const float* __restrict__ feats,
                                          const float* __restrict__ ws,
                                          float* __restrict__ g) {
    __shared__ float sw[N_ * 80];
    __shared__ float vlds[KCHUNK * N_];
    const int bid = blockIdx.x;          // 256 blocks: b(2) x kc(32) x dt(4)
    const int b = bid >> 7;
    const int rest = bid & 127;
    const int kc = rest >> 2;
    const int dt = rest & 3;
    const int t = threadIdx.x;
    const int k0 = kc * KCHUNK;

    for (int i = t; i < N_ * 80; i += 256)
        sw[i] = ws[OFF_BOXW + (size_t)b * N_ * 80 + i];
    __syncthreads();
    const float* ifn = ws + OFF_IFN + (size_t)b * K_;
    for (int i = t; i < KCHUNK * N_; i += 256) {
        int kk = i >> 5, n = i & 31;
        int k = k0 + kk;
        int pq = k / P_;
        int q = k - pq * P_;
        vlds[kk * N_ + n] = sw[n * 80 + pq] * sw[n * 80 + P_ + q] * ifn[k];
    }
    __syncthreads();

    float acc[N_];
    #pragma unroll
    for (int n = 0; n < N_; ++n) acc[n] = 0.f;

    const float* fp = feats + ((size_t)b * K_ + k0) * D_ + dt * 256 + t;
    #pragma unroll
    for (int gi = 0; gi < 5; ++gi) {
        float f[10];
        #pragma unroll
        for (int u = 0; u < 10; ++u) f[u] = fp[(size_t)(gi * 10 + u) * D_];  // 10 loads in flight
        #pragma unroll
        for (int u = 0; u < 10; ++u) {
            const float4* vp = (const float4*)&vlds[(gi * 10 + u) * N_];
            #pragma unroll
            for (int j = 0; j < 8; ++j) {            // broadcast b128 reads
                float4 v4 = vp[j];
                acc[4 * j + 0] = fmaf(v4.x, f[u], acc[4 * j + 0]);
                acc[4 * j + 1] = fmaf(v4.y, f[u], acc[4 * j + 1]);
                acc[4 * j + 2] = fmaf(v4.z, f[u], acc[4 * j + 2]);
                acc[4 * j + 3] = fmaf(v4.w, f[u], acc[4 * j + 3]);
            }
        }
    }
    float* o = g + (size_t)b * N_ * D_ + dt * 256 + t;
    #pragma unroll
    for (int n = 0; n < N_; ++n) atomicAdd(&o[(size_t)n * D_], acc[n]);
}

// ---- Kernel C: out[bn][c] = (1/|e_c|) * <g[bn,:], emb[c,:]> ----
__global__ __launch_bounds__(256) void kC(const float* __restrict__ emb,
                                          const float* __restrict__ g,
                                          const float* __restrict__ ien,
                                          float* __restrict__ out) {
    __shared__ float4 g4[D_ / 4];
    __shared__ float part[256];
    const int bid = blockIdx.x;      // 256 blocks: bn(64) x ct(4)
    const int bn = bid >> 2;
    const int ct = bid & 3;
    const int t = threadIdx.x;

    g4[t] = ((const float4*)(g + (size_t)bn * D_))[t];
    __syncthreads();

    const int cl = t & 63;
    const int dq = t >> 6;              // wave-uniform -> broadcast LDS reads
    const int c = ct * 64 + cl;
    const float4* e4 = (const float4*)(emb + (size_t)c * D_) + dq * 64;
    const float4* gg = g4 + dq * 64;
    float partial = 0.f;
    #pragma unroll 8
    for (int i = 0; i < 64; ++i) {
        float4 e = e4[i];
        float4 gv = gg[i];
        partial += e.x * gv.x + e.y * gv.y + e.z * gv.z + e.w * gv.w;
    }
    part[t] = partial;
    __syncthreads();
    if (t < 64) {
        int c2 = ct * 64 + t;
        float val = part[t] + part[64 + t] + part[128 + t] + part[192 + t];
        out[(size_t)bn * C_ + c2] = val * ien[c2];
    }
}

extern "C" void kernel_launch(void* const* d_in, const int* in_sizes, int n_in,
                              void* d_out, int out_size, void* d_ws, size_t ws_size,
                              hipStream_t stream) {
    const float* feats = (const float*)d_in[0];
    const float* emb   = (const float*)d_in[1];
    const int*   boxes = (const int*)d_in[2];
    float* out = (float*)d_out;
    float* ws  = (float*)d_ws;

    kA<<<B_ * K_ + C_ + B_ * N_, 256, 0, stream>>>(feats, emb, boxes, ws);
    kB<<<B_ * KC_ * 4, 256, 0, stream>>>(feats, ws, ws + OFF_G);
    kC<<<B_ * N_ * 4, 256, 0, stream>>>(emb, ws + OFF_G, ws + OFF_IEN, out);
}